// Round 6
// baseline (748.617 us; speedup 1.0000x reference)
//
#include <hip/hip_runtime.h>

// SparseResidualBlock on MI355X (gfx950).
// Round 8: R4 A-path (verified: global_load_lds dbuf, drain-after-compute) +
// B in REGISTERS with one-chunk-ahead prefetch (fix of R7's cold-B regression:
// MfmaUtil 17.8%, every chunk opened with a serial L2 round-trip for B).
//  - Per chunk: stage(c+1) -> compute(c, bX) -> loadB(c+2)->bX -> vmcnt(0)
//    -> s_barrier. WAR on bX prevents clobber; B(c+2) has a full chunk to land.
//  - Strictly NAMED B sets bE/bO, literal parities, pairwise loop: no dynamic
//    register-array indexing (R5 spill lesson, rule #20).
//  - LDS 32KB (A dbuf only) + launch_bounds(256,3) caps VGPR at 170
//    -> 3 blocks/CU (was 2): covers the drain tails.
// Spill tripwire for next round: WRITE_SIZE must stay ~77MB, VGPR <= 170.
// Glue: folded-stats BN kernels, fp16 tmp (verified R5/R7).

#define N_ACT 300000
#define NTAP  9
#define EPSV  1e-4f

using f16x8 = __attribute__((ext_vector_type(8))) _Float16;
using f32x4 = __attribute__((ext_vector_type(4))) float;

// ---- workspace layout (bytes) ----
#define OFF_PH    0UL                     // 76,800,000 : fp16 feature plane 300000x128
#define OFF_TMP   76800000UL              // 76,800,000 : fp16 conv output
#define OFF_W1    230400000UL             // 294,912 : 18 chunks x 8192 shorts (B-frag layout)
#define OFF_W2    (OFF_W1 + 294912UL)
#define OFF_STATS (OFF_W2 + 294912UL)     // 512 floats: sum1, sq1, sum2, sq2
#define OFF_ZBUF  (OFF_STATS + 2048UL)    // 256 B zeros (gather target for idx<0)

__device__ __forceinline__ unsigned short f2h(float v) {
  _Float16 h = (_Float16)v;               // RNE
  return __builtin_bit_cast(unsigned short, h);
}

// ---- prep: fp16 weight images in B-fragment-coalesced layout; zero stats ----
// img[chunk][n6][ks][nt][ln][j] = W[tap][ch*64 + (ks*4+(ln>>4))*8 + j][n6*64 + nt*16 + (ln&15)]
// (chunk = tap*2+ch; shorts offset = chunk*8192 + n6*4096 + ks*2048 + nt*512 + ln*8 + j)
__global__ void prep_kernel(const float* __restrict__ W1, const float* __restrict__ W2,
                            unsigned short* __restrict__ w1, unsigned short* __restrict__ w2,
                            float* __restrict__ zstats) {
  int b = blockIdx.x, t = threadIdx.x;
  if (b == 36) {                          // stats (512 f) + zbuf (64 f) zeroing
    for (int i = t; i < 576; i += 256) zstats[i] = 0.f;
    return;
  }
  int w = b / 18, rem = b % 18;
  int tap = rem >> 1, ch = rem & 1;
  const float* W = w ? W2 : W1;
  unsigned short* o = w ? w2 : w1;
  for (int it = 0; it < 4; ++it) {
    int tp = it * 256 + t;                // 0..1023 -> (n6, ks, nt, ln)
    int ln = tp & 63, nt = (tp >> 6) & 3, ks = (tp >> 8) & 1, n6 = tp >> 9;
    int n     = n6 * 64 + nt * 16 + (ln & 15);
    int kbase = ch * 64 + (ks * 4 + (ln >> 4)) * 8;
    unsigned short v8[8];
    for (int j = 0; j < 8; ++j)
      v8[j] = f2h(W[tap * 16384 + (kbase + j) * 128 + n]);
    *(uint4*)(o + rem * 8192 + n6 * 4096 + ks * 2048 + nt * 512 + ln * 8) = *(uint4*)v8;
  }
}

// ---- x -> fp16 plane (8 elems/thread) ----
__global__ void tohalf_kernel(const float* __restrict__ x, unsigned short* __restrict__ ph) {
  int i = (blockIdx.x * 256 + threadIdx.x) * 8;
  float4 a = *(const float4*)(x + i);
  float4 b = *(const float4*)(x + i + 4);
  uint4 p;
  p.x = (unsigned)f2h(a.x) | ((unsigned)f2h(a.y) << 16);
  p.y = (unsigned)f2h(a.z) | ((unsigned)f2h(a.w) << 16);
  p.z = (unsigned)f2h(b.x) | ((unsigned)f2h(b.y) << 16);
  p.w = (unsigned)f2h(b.z) | ((unsigned)f2h(b.w) << 16);
  *(uint4*)(ph + i) = p;
}

// ---- gathered GEMM conv: A via global_load_lds dbuf, B reg-prefetched ----
__global__ __launch_bounds__(256, 3)
void conv_kernel(const unsigned short* __restrict__ pH, const int* __restrict__ nbr,
                 const unsigned short* __restrict__ wH,
                 unsigned short* __restrict__ outp, float* __restrict__ ssum, float* __restrict__ ssq,
                 const unsigned short* __restrict__ zbuf) {
  __shared__ char smem[32768];            // A double buffer only (2 x 16KB)
  const int t  = threadIdx.x;
  const int wv = t >> 6, ln = t & 63;
  const int m0 = blockIdx.x * 128;
  const int rs = ln >> 3, sg = ln & 7;      // staging coords
  const int lane16 = ln & 15, g = ln >> 4;  // mfma frag coords

  f32x4 acc[16];
#pragma unroll
  for (int i = 0; i < 16; ++i) acc[i] = f32x4{0.f, 0.f, 0.f, 0.f};

  // stage A chunk c into parity-p LDS buffer (idx loaded inline, L1-hot lines)
  auto stage = [&](int c, int p) {
    const int tap = c >> 1, ch = c & 1;
#pragma unroll
    for (int it = 0; it < 4; ++it) {
      int r     = wv * 32 + it * 8 + rs;
      int gm    = m0 + r;
      int id    = (gm < N_ACT) ? nbr[gm * 9 + tap] : -1;
      int sigma = sg ^ (r & 7);
      const unsigned short* gs = (id >= 0) ? (pH + (long)id * 128 + ch * 64 + sigma * 8)
                                           : (zbuf + sigma * 8);
      int lo = p * 16384 + r * 128 + sg * 16;    // wave-uniform base + ln*16
      __builtin_amdgcn_global_load_lds((const __attribute__((address_space(1))) void*)gs,
                                       (__attribute__((address_space(3))) void*)(smem + lo), 16, 0, 0);
    }
  };

  // B fragments for chunk c: global -> named regs (8 x 16B, coalesced)
  auto loadB = [&](int c, f16x8* b) {
    const unsigned short* wbase = wH + c * 8192 + (wv >> 1) * 4096 + ln * 8;
#pragma unroll
    for (int nt = 0; nt < 4; ++nt) b[nt]     = *(const f16x8*)(wbase + nt * 512);
#pragma unroll
    for (int nt = 0; nt < 4; ++nt) b[4 + nt] = *(const f16x8*)(wbase + 2048 + nt * 512);
  };

  // compute chunk from parity-p A buffer; B from resident regs
  auto compute = [&](int p, const f16x8* b) {
    const char* bufA = smem + p * 16384;
    {
      f16x8 ah[4];
      int sigma = g;                      // ks = 0
#pragma unroll
      for (int mt = 0; mt < 4; ++mt) {
        int m = (wv & 1) * 64 + mt * 16 + lane16;
        ah[mt] = *(const f16x8*)(bufA + m * 128 + ((sigma ^ (m & 7)) * 16));
      }
#pragma unroll
      for (int mt = 0; mt < 4; ++mt)
#pragma unroll
        for (int nt = 0; nt < 4; ++nt)
          acc[mt * 4 + nt] = __builtin_amdgcn_mfma_f32_16x16x32_f16(ah[mt], b[nt], acc[mt * 4 + nt], 0, 0, 0);
    }
    {
      f16x8 ah[4];
      int sigma = 4 + g;                  // ks = 1
#pragma unroll
      for (int mt = 0; mt < 4; ++mt) {
        int m = (wv & 1) * 64 + mt * 16 + lane16;
        ah[mt] = *(const f16x8*)(bufA + m * 128 + ((sigma ^ (m & 7)) * 16));
      }
#pragma unroll
      for (int mt = 0; mt < 4; ++mt)
#pragma unroll
        for (int nt = 0; nt < 4; ++nt)
          acc[mt * 4 + nt] = __builtin_amdgcn_mfma_f32_16x16x32_f16(ah[mt], b[4 + nt], acc[mt * 4 + nt], 0, 0, 0);
    }
  };

  f16x8 bE[8], bO[8];                     // named B sets: even / odd chunks

  // prologue: land chunk 0 in LDS; B(0), B(1) resident
  stage(0, 0);
  loadB(0, bE);
  loadB(1, bO);
  asm volatile("s_waitcnt vmcnt(0)" ::: "memory");
  __builtin_amdgcn_sched_barrier(0);
  __builtin_amdgcn_s_barrier();

  for (int tt = 0; tt < 8; ++tt) {        // chunks 2tt (bE) and 2tt+1 (bO)
    int c = 2 * tt;
    // --- even chunk: parity 0, B = bE ---
    stage(c + 1, 1);
    compute(0, bE);
    loadB(c + 2, bE);                     // bE free (WAR); lands next section
    asm volatile("s_waitcnt vmcnt(0)" ::: "memory");
    __builtin_amdgcn_sched_barrier(0);
    __builtin_amdgcn_s_barrier();
    // --- odd chunk: parity 1, B = bO ---
    stage(c + 2, 0);
    compute(1, bO);
    loadB(c + 3, bO);
    asm volatile("s_waitcnt vmcnt(0)" ::: "memory");
    __builtin_amdgcn_sched_barrier(0);
    __builtin_amdgcn_s_barrier();
  }
  // tail: chunks 16 (bE, parity 0) and 17 (bO, parity 1); B already resident
  stage(17, 1);
  compute(0, bE);
  asm volatile("s_waitcnt vmcnt(0)" ::: "memory");
  __builtin_amdgcn_sched_barrier(0);
  __builtin_amdgcn_s_barrier();
  compute(1, bO);

  // epilogue: fp16 store + per-channel sum/sumsq (pad rows are exactly 0)
  int rowbase = m0 + (wv & 1) * 64;
  int colbase = (wv >> 1) * 64;
  float s[4], q[4];
#pragma unroll
  for (int nt = 0; nt < 4; ++nt) { s[nt] = 0.f; q[nt] = 0.f; }
#pragma unroll
  for (int mt = 0; mt < 4; ++mt)
#pragma unroll
    for (int nt = 0; nt < 4; ++nt)
#pragma unroll
      for (int r = 0; r < 4; ++r) {
        float v  = acc[mt * 4 + nt][r];
        int  row = rowbase + mt * 16 + g * 4 + r;
        int  col = colbase + nt * 16 + lane16;
        if (row < N_ACT) outp[row * 128 + col] = f2h(v);
        s[nt] += v; q[nt] += v * v;
      }
  __syncthreads();
  float* sbuf = (float*)smem;           // [4 waves][64 cols]
  float* qbuf = ((float*)smem) + 256;
#pragma unroll
  for (int nt = 0; nt < 4; ++nt) {
    float sv = s[nt], qv = q[nt];
    sv += __shfl_xor(sv, 16, 64); sv += __shfl_xor(sv, 32, 64);
    qv += __shfl_xor(qv, 16, 64); qv += __shfl_xor(qv, 32, 64);
    if (ln < 16) { sbuf[wv * 64 + nt * 16 + ln] = sv; qbuf[wv * 64 + nt * 16 + ln] = qv; }
  }
  __syncthreads();
  if (t < 128) {
    int c = t;
    float tot = (c < 64) ? (sbuf[c] + sbuf[64 + c]) : (sbuf[128 + (c - 64)] + sbuf[192 + (c - 64)]);
    atomicAdd(ssum + c, tot);
  } else {
    int c = t - 128;
    float tot = (c < 64) ? (qbuf[c] + qbuf[64 + c]) : (qbuf[128 + (c - 64)] + qbuf[192 + (c - 64)]);
    atomicAdd(ssq + c, tot);
  }
}

// ---- BN + ReLU -> fp16 plane (feeds conv2); stats folded in per-thread ----
__global__ void bn_relu_tohalf_kernel(const unsigned short* __restrict__ tmp,
                                      const float* __restrict__ ssum, const float* __restrict__ ssq,
                                      const float* __restrict__ gamma, const float* __restrict__ beta,
                                      unsigned short* __restrict__ ph) {
  int i = (blockIdx.x * 256 + threadIdx.x) * 8;
  int c = i & 127;
  f16x8 v = *(const f16x8*)(tmp + i);
  float sc[8], bs[8];
#pragma unroll
  for (int j = 0; j < 8; ++j) {
    float mean = ssum[c + j] * (1.f / N_ACT);
    float var  = ssq[c + j] * (1.f / N_ACT) - mean * mean;
    float k    = rsqrtf(var + EPSV) * gamma[c + j];
    sc[j] = k; bs[j] = beta[c + j] - mean * k;
  }
  uint4 p;
  float y0 = fmaxf((float)v[0] * sc[0] + bs[0], 0.f);
  float y1 = fmaxf((float)v[1] * sc[1] + bs[1], 0.f);
  float y2 = fmaxf((float)v[2] * sc[2] + bs[2], 0.f);
  float y3 = fmaxf((float)v[3] * sc[3] + bs[3], 0.f);
  float y4 = fmaxf((float)v[4] * sc[4] + bs[4], 0.f);
  float y5 = fmaxf((float)v[5] * sc[5] + bs[5], 0.f);
  float y6 = fmaxf((float)v[6] * sc[6] + bs[6], 0.f);
  float y7 = fmaxf((float)v[7] * sc[7] + bs[7], 0.f);
  p.x = (unsigned)f2h(y0) | ((unsigned)f2h(y1) << 16);
  p.y = (unsigned)f2h(y2) | ((unsigned)f2h(y3) << 16);
  p.z = (unsigned)f2h(y4) | ((unsigned)f2h(y5) << 16);
  p.w = (unsigned)f2h(y6) | ((unsigned)f2h(y7) << 16);
  *(uint4*)(ph + i) = p;
}

// ---- BN2 + residual + ReLU (stats folded in per-thread) ----
__global__ void final_kernel(const unsigned short* __restrict__ tmp,
                             const float* __restrict__ ssum, const float* __restrict__ ssq,
                             const float* __restrict__ gamma, const float* __restrict__ beta,
                             const float* __restrict__ x, float* __restrict__ outp) {
  int i = (blockIdx.x * 256 + threadIdx.x) * 8;
  int c = i & 127;
  f16x8 v = *(const f16x8*)(tmp + i);
  float sc[8], bs[8];
#pragma unroll
  for (int j = 0; j < 8; ++j) {
    float mean = ssum[c + j] * (1.f / N_ACT);
    float var  = ssq[c + j] * (1.f / N_ACT) - mean * mean;
    float k    = rsqrtf(var + EPSV) * gamma[c + j];
    sc[j] = k; bs[j] = beta[c + j] - mean * k;
  }
  float4 x0 = *(const float4*)(x + i);
  float4 x1 = *(const float4*)(x + i + 4);
  float4 o0, o1;
  o0.x = fmaxf((float)v[0] * sc[0] + bs[0] + x0.x, 0.f);
  o0.y = fmaxf((float)v[1] * sc[1] + bs[1] + x0.y, 0.f);
  o0.z = fmaxf((float)v[2] * sc[2] + bs[2] + x0.z, 0.f);
  o0.w = fmaxf((float)v[3] * sc[3] + bs[3] + x0.w, 0.f);
  o1.x = fmaxf((float)v[4] * sc[4] + bs[4] + x1.x, 0.f);
  o1.y = fmaxf((float)v[5] * sc[5] + bs[5] + x1.y, 0.f);
  o1.z = fmaxf((float)v[6] * sc[6] + bs[6] + x1.z, 0.f);
  o1.w = fmaxf((float)v[7] * sc[7] + bs[7] + x1.w, 0.f);
  *(float4*)(outp + i) = o0;
  *(float4*)(outp + i + 4) = o1;
}

extern "C" void kernel_launch(void* const* d_in, const int* in_sizes, int n_in,
                              void* d_out, int out_size, void* d_ws, size_t ws_size,
                              hipStream_t stream) {
  const float* x   = (const float*)d_in[0];
  const int*   nbr = (const int*)d_in[1];
  const float* W1  = (const float*)d_in[2];
  const float* g1  = (const float*)d_in[3];
  const float* b1  = (const float*)d_in[4];
  const float* W2  = (const float*)d_in[5];
  const float* g2  = (const float*)d_in[6];
  const float* b2  = (const float*)d_in[7];
  float* out = (float*)d_out;
  char*  ws  = (char*)d_ws;

  unsigned short* ph  = (unsigned short*)(ws + OFF_PH);
  unsigned short* tmp = (unsigned short*)(ws + OFF_TMP);   // fp16 conv out
  unsigned short* w1  = (unsigned short*)(ws + OFF_W1);
  unsigned short* w2  = (unsigned short*)(ws + OFF_W2);
  float*          st  = (float*)(ws + OFF_STATS);     // sum1, sq1, sum2, sq2 (128 each)
  unsigned short* zb  = (unsigned short*)(ws + OFF_ZBUF);

  prep_kernel<<<37, 256, 0, stream>>>(W1, W2, w1, w2, st);
  tohalf_kernel<<<18750, 256, 0, stream>>>(x, ph);                       // 38.4M/(256*8)
  conv_kernel<<<2344, 256, 0, stream>>>(ph, nbr, w1, tmp, st, st + 128, zb);
  bn_relu_tohalf_kernel<<<18750, 256, 0, stream>>>(tmp, st, st + 128, g1, b1, ph);
  conv_kernel<<<2344, 256, 0, stream>>>(ph, nbr, w2, tmp, st + 256, st + 384, zb);
  final_kernel<<<18750, 256, 0, stream>>>(tmp, st + 256, st + 384, g2, b2, x, out);
}

// Round 7
// 563.147 us; speedup vs baseline: 1.3293x; 1.3293x over previous
//
#include <hip/hip_runtime.h>

// SparseResidualBlock on MI355X (gfx950).
// Round 9: conv REVERTED to the exact R4 kernel (verified 124.5us twice:
// A gathers + B both via global_load_lds into 2x(16+16)KB LDS dbuf, 2-phase
// { stage(c+1) -> compute(c) -> vmcnt(0) -> s_barrier }). Both B-in-register
// variants (R5 dynamic arrays, R8 named arrays) were spilled by the compiler
// (WRITE_SIZE +52..240MB, VGPR capped 84..128) -> arc abandoned.
// Glue changes this round (conv is the control):
//  - prep fused into the tohalf launch (prep's 37 latency-bound blocks ride a
//    2048-block grid-stride launch instead of serializing the stream head).
//  - tohalf / bn_relu / final converted to 2048-block grid-stride (G11);
//    folded-BN scale/bias hoisted out of the loop (stride % 128 == 0 so the
//    channel phase is iteration-invariant).
// Glue totals ~320us across rounds while ideal traffic is ~150us -> not
// BW-bound; this round isolates launch/serialization overhead.

#define N_ACT 300000
#define NTAP  9
#define EPSV  1e-4f
#define GSB   2048          // grid-stride blocks for streaming kernels
#define NWU   4800000       // 38.4M elems / 8 per thread

using f16x8 = __attribute__((ext_vector_type(8))) _Float16;
using f32x4 = __attribute__((ext_vector_type(4))) float;

// ---- workspace layout (bytes) ----
#define OFF_PH    0UL                     // 76,800,000 : fp16 feature plane 300000x128
#define OFF_TMP   76800000UL              // 76,800,000 : fp16 conv output
#define OFF_W1    230400000UL             // 294,912 : 9 taps x 2 chunks x 128 n x 64 k fp16
#define OFF_W2    (OFF_W1 + 294912UL)
#define OFF_STATS (OFF_W2 + 294912UL)     // 512 floats: sum1, sq1, sum2, sq2
#define OFF_ZBUF  (OFF_STATS + 2048UL)    // 256 B zeros (gather target for idx<0)

__device__ __forceinline__ unsigned short f2h(float v) {
  _Float16 h = (_Float16)v;               // RNE
  return __builtin_bit_cast(unsigned short, h);
}

// ---- fused: x -> fp16 plane (grid-stride) + weight prep + stats zeroing ----
// blocks [0, GSB): tohalf grid-stride. blocks [GSB, GSB+37): prep (R4 logic).
// prep image[(tap*2+ch)*8192 + n*64 + s*8 + j] = W[tap][ch*64+8*(s^(n&7))+j][n]
__global__ void tohalf_prep_kernel(const float* __restrict__ x, unsigned short* __restrict__ ph,
                                   const float* __restrict__ W1, const float* __restrict__ W2,
                                   unsigned short* __restrict__ w1, unsigned short* __restrict__ w2,
                                   float* __restrict__ zstats) {
  int pb = blockIdx.x - GSB;
  if (pb >= 0) {                          // ---- prep part ----
    int t = threadIdx.x;
    if (pb == 36) {                       // stats (512 f) + zbuf (64 f) zeroing
      for (int i = t; i < 576; i += 256) zstats[i] = 0.f;
      return;
    }
    int w = pb / 18, rem = pb % 18;
    int tap = rem >> 1, ch = rem & 1;
    const float* W = w ? W2 : W1;
    unsigned short* o = w ? w2 : w1;
    int n  = t >> 1;
    int s0 = (t & 1) * 4;
    for (int s = s0; s < s0 + 4; ++s) {
      int sigma = s ^ (n & 7);
      for (int j = 0; j < 8; ++j) {
        int   k = ch * 64 + sigma * 8 + j;
        float v = W[tap * 16384 + k * 128 + n];
        o[rem * 8192 + n * 64 + s * 8 + j] = f2h(v);
      }
    }
    return;
  }
  // ---- tohalf part (grid-stride, 8 elems/work-unit) ----
  for (long u = blockIdx.x * 256 + threadIdx.x; u < NWU; u += (long)GSB * 256) {
    long i = u * 8;
    float4 a = *(const float4*)(x + i);
    float4 b = *(const float4*)(x + i + 4);
    uint4 p;
    p.x = (unsigned)f2h(a.x) | ((unsigned)f2h(a.y) << 16);
    p.y = (unsigned)f2h(a.z) | ((unsigned)f2h(a.w) << 16);
    p.z = (unsigned)f2h(b.x) | ((unsigned)f2h(b.y) << 16);
    p.w = (unsigned)f2h(b.z) | ((unsigned)f2h(b.w) << 16);
    *(uint4*)(ph + i) = p;
  }
}

// ---- gathered GEMM conv (EXACT R4 kernel, verified 124.5us) ----
// 18 chunks (tap,ch). LDS: A dbuf [0,32K), B dbuf [32K,64K). 2 blocks/CU.
// Per chunk: stage(c+1, p^1) || compute(c, p) -> vmcnt(0) -> s_barrier.
__global__ __launch_bounds__(256, 2)
void conv_kernel(const unsigned short* __restrict__ pH, const int* __restrict__ nbr,
                 const unsigned short* __restrict__ wH,
                 unsigned short* __restrict__ outp, float* __restrict__ ssum, float* __restrict__ ssq,
                 const unsigned short* __restrict__ zbuf) {
  __shared__ char smem[65536];
  const int t  = threadIdx.x;
  const int wv = t >> 6, ln = t & 63;
  const int m0 = blockIdx.x * 128;
  const int rs = ln >> 3, sg = ln & 7;      // staging coords
  const int lane16 = ln & 15, g = ln >> 4;  // mfma frag coords

  // preload ALL tap indices (static indexing after full unroll — registers)
  int idx[NTAP][4];
#pragma unroll
  for (int tap = 0; tap < NTAP; ++tap)
#pragma unroll
    for (int it = 0; it < 4; ++it) {
      int gm = m0 + wv * 32 + it * 8 + rs;
      idx[tap][it] = (gm < N_ACT) ? nbr[gm * 9 + tap] : -1;
    }

  f32x4 acc[16];
#pragma unroll
  for (int i = 0; i < 16; ++i) acc[i] = f32x4{0.f, 0.f, 0.f, 0.f};

  auto stage = [&](int c, int p) {
    const int tap = c >> 1, ch = c & 1;
    // A (gather) via global_load_lds width16 into parity-p buffer
#pragma unroll
    for (int it = 0; it < 4; ++it) {
      int r     = wv * 32 + it * 8 + rs;
      int sigma = sg ^ (r & 7);
      int id    = idx[tap][it];
      long off  = (long)(id >= 0 ? id : 0) * 128 + ch * 64 + sigma * 8;
      const unsigned short* gs = (id >= 0) ? (pH + off) : (zbuf + sigma * 8);
      int lo = p * 16384 + r * 128 + sg * 16;    // wave-uniform base + ln*16
      __builtin_amdgcn_global_load_lds((const __attribute__((address_space(1))) void*)gs,
                                       (__attribute__((address_space(3))) void*)(smem + lo), 16, 0, 0);
    }
    // B (pre-swizzled contiguous 16KB image, L2-hot)
    const char* gb = (const char*)wH + (tap * 2 + ch) * 16384;
#pragma unroll
    for (int it = 0; it < 4; ++it) {
      int o = wv * 4096 + it * 1024 + ln * 16;
      __builtin_amdgcn_global_load_lds((const __attribute__((address_space(1))) void*)(gb + o),
                                       (__attribute__((address_space(3))) void*)(smem + 32768 + p * 16384 + o), 16, 0, 0);
    }
  };

  auto compute = [&](int p) {
    const char* bufA = smem + p * 16384;
    const char* bufB = smem + 32768 + p * 16384;
#pragma unroll
    for (int ks = 0; ks < 2; ++ks) {
      f16x8 ah[4], bh[4];
      int sigma = ks * 4 + g;
#pragma unroll
      for (int mt = 0; mt < 4; ++mt) {
        int m = (wv & 1) * 64 + mt * 16 + lane16;
        ah[mt] = *(const f16x8*)(bufA + m * 128 + ((sigma ^ (m & 7)) * 16));
      }
#pragma unroll
      for (int nt = 0; nt < 4; ++nt) {
        int n = (wv >> 1) * 64 + nt * 16 + lane16;
        bh[nt] = *(const f16x8*)(bufB + n * 128 + ((sigma ^ (n & 7)) * 16));
      }
#pragma unroll
      for (int mt = 0; mt < 4; ++mt)
#pragma unroll
        for (int nt = 0; nt < 4; ++nt)
          acc[mt * 4 + nt] = __builtin_amdgcn_mfma_f32_16x16x32_f16(ah[mt], bh[nt], acc[mt * 4 + nt], 0, 0, 0);
    }
  };

  // prologue: land chunk 0
  stage(0, 0);
  asm volatile("s_waitcnt vmcnt(0)" ::: "memory");
  __builtin_amdgcn_sched_barrier(0);
  __builtin_amdgcn_s_barrier();

#pragma unroll
  for (int c = 0; c < 17; ++c) {
    stage(c + 1, (c + 1) & 1);    // issue next chunk's loads (other parity)
    compute(c & 1);               // compute current chunk (overlaps loads)
    asm volatile("s_waitcnt vmcnt(0)" ::: "memory");  // next chunk landed
    __builtin_amdgcn_sched_barrier(0);
    __builtin_amdgcn_s_barrier(); // all waves done reading parity c&1
  }
  compute(1);                     // chunk 17 (parity 1), already landed

  // epilogue: fp16 store + per-channel sum/sumsq (pad rows are exactly 0)
  int rowbase = m0 + (wv & 1) * 64;
  int colbase = (wv >> 1) * 64;
  float s[4], q[4];
#pragma unroll
  for (int nt = 0; nt < 4; ++nt) { s[nt] = 0.f; q[nt] = 0.f; }
#pragma unroll
  for (int mt = 0; mt < 4; ++mt)
#pragma unroll
    for (int nt = 0; nt < 4; ++nt)
#pragma unroll
      for (int r = 0; r < 4; ++r) {
        float v  = acc[mt * 4 + nt][r];
        int  row = rowbase + mt * 16 + g * 4 + r;
        int  col = colbase + nt * 16 + lane16;
        if (row < N_ACT) outp[row * 128 + col] = f2h(v);
        s[nt] += v; q[nt] += v * v;
      }
  __syncthreads();
  float* sbuf = (float*)smem;           // [4 waves][64 cols]
  float* qbuf = ((float*)smem) + 256;
#pragma unroll
  for (int nt = 0; nt < 4; ++nt) {
    float sv = s[nt], qv = q[nt];
    sv += __shfl_xor(sv, 16, 64); sv += __shfl_xor(sv, 32, 64);
    qv += __shfl_xor(qv, 16, 64); qv += __shfl_xor(qv, 32, 64);
    if (ln < 16) { sbuf[wv * 64 + nt * 16 + ln] = sv; qbuf[wv * 64 + nt * 16 + ln] = qv; }
  }
  __syncthreads();
  if (t < 128) {
    int c = t;
    float tot = (c < 64) ? (sbuf[c] + sbuf[64 + c]) : (sbuf[128 + (c - 64)] + sbuf[192 + (c - 64)]);
    atomicAdd(ssum + c, tot);
  } else {
    int c = t - 128;
    float tot = (c < 64) ? (qbuf[c] + qbuf[64 + c]) : (qbuf[128 + (c - 64)] + qbuf[192 + (c - 64)]);
    atomicAdd(ssq + c, tot);
  }
}

// ---- BN + ReLU -> fp16 plane (grid-stride; folded stats hoisted) ----
__global__ void bn_relu_tohalf_kernel(const unsigned short* __restrict__ tmp,
                                      const float* __restrict__ ssum, const float* __restrict__ ssq,
                                      const float* __restrict__ gamma, const float* __restrict__ beta,
                                      unsigned short* __restrict__ ph) {
  long u0 = blockIdx.x * 256 + threadIdx.x;
  int  c  = (int)((u0 * 8) & 127);        // stride (GSB*256*8) % 128 == 0 -> invariant
  float sc[8], bs[8];
#pragma unroll
  for (int j = 0; j < 8; ++j) {
    float mean = ssum[c + j] * (1.f / N_ACT);
    float var  = ssq[c + j] * (1.f / N_ACT) - mean * mean;
    float k    = rsqrtf(var + EPSV) * gamma[c + j];
    sc[j] = k; bs[j] = beta[c + j] - mean * k;
  }
  for (long u = u0; u < NWU; u += (long)GSB * 256) {
    long i = u * 8;
    f16x8 v = *(const f16x8*)(tmp + i);
    float y0 = fmaxf((float)v[0] * sc[0] + bs[0], 0.f);
    float y1 = fmaxf((float)v[1] * sc[1] + bs[1], 0.f);
    float y2 = fmaxf((float)v[2] * sc[2] + bs[2], 0.f);
    float y3 = fmaxf((float)v[3] * sc[3] + bs[3], 0.f);
    float y4 = fmaxf((float)v[4] * sc[4] + bs[4], 0.f);
    float y5 = fmaxf((float)v[5] * sc[5] + bs[5], 0.f);
    float y6 = fmaxf((float)v[6] * sc[6] + bs[6], 0.f);
    float y7 = fmaxf((float)v[7] * sc[7] + bs[7], 0.f);
    uint4 p;
    p.x = (unsigned)f2h(y0) | ((unsigned)f2h(y1) << 16);
    p.y = (unsigned)f2h(y2) | ((unsigned)f2h(y3) << 16);
    p.z = (unsigned)f2h(y4) | ((unsigned)f2h(y5) << 16);
    p.w = (unsigned)f2h(y6) | ((unsigned)f2h(y7) << 16);
    *(uint4*)(ph + i) = p;
  }
}

// ---- BN2 + residual + ReLU (grid-stride; folded stats hoisted) ----
__global__ void final_kernel(const unsigned short* __restrict__ tmp,
                             const float* __restrict__ ssum, const float* __restrict__ ssq,
                             const float* __restrict__ gamma, const float* __restrict__ beta,
                             const float* __restrict__ x, float* __restrict__ outp) {
  long u0 = blockIdx.x * 256 + threadIdx.x;
  int  c  = (int)((u0 * 8) & 127);
  float sc[8], bs[8];
#pragma unroll
  for (int j = 0; j < 8; ++j) {
    float mean = ssum[c + j] * (1.f / N_ACT);
    float var  = ssq[c + j] * (1.f / N_ACT) - mean * mean;
    float k    = rsqrtf(var + EPSV) * gamma[c + j];
    sc[j] = k; bs[j] = beta[c + j] - mean * k;
  }
  for (long u = u0; u < NWU; u += (long)GSB * 256) {
    long i = u * 8;
    f16x8 v = *(const f16x8*)(tmp + i);
    float4 x0 = *(const float4*)(x + i);
    float4 x1 = *(const float4*)(x + i + 4);
    float4 o0, o1;
    o0.x = fmaxf((float)v[0] * sc[0] + bs[0] + x0.x, 0.f);
    o0.y = fmaxf((float)v[1] * sc[1] + bs[1] + x0.y, 0.f);
    o0.z = fmaxf((float)v[2] * sc[2] + bs[2] + x0.z, 0.f);
    o0.w = fmaxf((float)v[3] * sc[3] + bs[3] + x0.w, 0.f);
    o1.x = fmaxf((float)v[4] * sc[4] + bs[4] + x1.x, 0.f);
    o1.y = fmaxf((float)v[5] * sc[5] + bs[5] + x1.y, 0.f);
    o1.z = fmaxf((float)v[6] * sc[6] + bs[6] + x1.z, 0.f);
    o1.w = fmaxf((float)v[7] * sc[7] + bs[7] + x1.w, 0.f);
    *(float4*)(outp + i) = o0;
    *(float4*)(outp + i + 4) = o1;
  }
}

extern "C" void kernel_launch(void* const* d_in, const int* in_sizes, int n_in,
                              void* d_out, int out_size, void* d_ws, size_t ws_size,
                              hipStream_t stream) {
  const float* x   = (const float*)d_in[0];
  const int*   nbr = (const int*)d_in[1];
  const float* W1  = (const float*)d_in[2];
  const float* g1  = (const float*)d_in[3];
  const float* b1  = (const float*)d_in[4];
  const float* W2  = (const float*)d_in[5];
  const float* g2  = (const float*)d_in[6];
  const float* b2  = (const float*)d_in[7];
  float* out = (float*)d_out;
  char*  ws  = (char*)d_ws;

  unsigned short* ph  = (unsigned short*)(ws + OFF_PH);
  unsigned short* tmp = (unsigned short*)(ws + OFF_TMP);   // fp16 conv out
  unsigned short* w1  = (unsigned short*)(ws + OFF_W1);
  unsigned short* w2  = (unsigned short*)(ws + OFF_W2);
  float*          st  = (float*)(ws + OFF_STATS);     // sum1, sq1, sum2, sq2 (128 each)
  unsigned short* zb  = (unsigned short*)(ws + OFF_ZBUF);

  tohalf_prep_kernel<<<GSB + 37, 256, 0, stream>>>(x, ph, W1, W2, w1, w2, st);
  conv_kernel<<<2344, 256, 0, stream>>>(ph, nbr, w1, tmp, st, st + 128, zb);
  bn_relu_tohalf_kernel<<<GSB, 256, 0, stream>>>(tmp, st, st + 128, g1, b1, ph);
  conv_kernel<<<2344, 256, 0, stream>>>(ph, nbr, w2, tmp, st + 256, st + 384, zb);
  final_kernel<<<GSB, 256, 0, stream>>>(tmp, st + 256, st + 384, g2, b2, x, out);
}